// Round 5
// baseline (2846.408 us; speedup 1.0000x reference)
//
#include <hip/hip_runtime.h>
#include <math.h>

#define BB   32
#define CIN  32
#define COUT 64
#define HH   128
#define WW   128
#define PLANE (HH*WW)          // 16384

// async global->LDS, width 4 (per-lane source, lane-linear LDS dest)
#define GLOAD_LDS4(g, l) __builtin_amdgcn_global_load_lds(                    \
    (const __attribute__((address_space(1))) void*)(g),                       \
    (__attribute__((address_space(3))) void*)(l), 4, 0, 0)

// symmetric padding index map (size 128, pad 2)
__device__ __forceinline__ int reflect(int p) {
    if (p < 0)   return -1 - p;      // -1->0, -2->1
    if (p > 127) return 255 - p;     // 128->127, 129->126
    return p;
}

// K0: repack weight [co][cin][kh][kw] -> wpk [(cin*25+k)][co]  (co fastest)
__global__ __launch_bounds__(256) void repack_w(const float* __restrict__ w,
                                                float* __restrict__ wpk) {
    int i = blockIdx.x * 256 + threadIdx.x;        // over 64*32*25 = 51200
    if (i >= COUT * CIN * 25) return;
    int co = i / (CIN * 25);
    int rm = i - co * (CIN * 25);                  // cin*25 + k
    wpk[rm * COUT + co] = w[i];
}

// K1: main 5x5 conv, symmetric pad, T3-lite pipelined global_load_lds staging.
// Block: 8 rows x 64 cols x 32 couts; 4 waves, wave wv owns rows 2wv,2wv+1.
// LDS: double-buffered chunk of 8 cin x (12x68 rows padded to 832-slab).
// grid: (32 tiles [16 h-tiles x 2 w-tiles], 2 cout-blocks, 32 batch)
__global__ __launch_bounds__(256, 4) void conv_main(const float* __restrict__ x,
                                                    const float* __restrict__ wpk,
                                                    float* __restrict__ y1) {
    __shared__ float Xs[2][8][832];                // 2 x 26624 B = 53248 B
    const int tid  = threadIdx.x;
    const int lane = tid & 63;
    const int wv   = tid >> 6;                     // wave 0..3
    const int h0   = (int)(blockIdx.x >> 1) * 8;
    const int w0   = (int)(blockIdx.x & 1) * 64;
    const int cob  = (int)blockIdx.y * 32;
    const int b    = (int)blockIdx.z;

    const float* xb = x + (size_t)b * CIN * PLANE;

    // per-lane source byte offsets for this wave's 26 loads (geometry is
    // identical for every chunk; reflect folded in; slab tail -> harmless xc[0])
    int voff[26];
#pragma unroll
    for (int t = 0; t < 26; ++t) {
        const int j  = wv + 4 * t;                 // load index 0..103
        const int e  = j * 64 + lane;              // flat element 0..6655
        const int ci = e / 832;                    // 8 ci-slabs of 832 (13 loads)
        const int ep = e - ci * 832;
        const int r  = ep / 68;
        const int c  = ep - r * 68;
        int off;
        if (ep >= 816) off = ci * PLANE * 4;       // pad tail: load xc[0]
        else {
            const int sh = reflect(h0 - 2 + r);
            const int sw = reflect(w0 - 2 + c);
            off = (ci * PLANE + sh * WW + sw) * 4;
        }
        voff[t] = off;
    }

    float acc[2][32];
#pragma unroll
    for (int r = 0; r < 2; ++r)
#pragma unroll
        for (int c = 0; c < 32; ++c) acc[r][c] = 0.f;

    // prologue: stage chunk 0 -> buf 0
    {
        const char* cb = (const char*)xb;
        char* lb = (char*)&Xs[0][0][0];
#pragma unroll
        for (int t = 0; t < 26; ++t)
            GLOAD_LDS4(cb + voff[t], lb + (wv + 4 * t) * 256);
    }

#pragma unroll 1
    for (int cc = 0; cc < 4; ++cc) {
        const int buf = cc & 1;
        if (cc < 3) {                              // prefetch chunk cc+1 -> buf^1
            const char* cb = (const char*)xb + (size_t)(cc + 1) * 8 * PLANE * 4;
            char* lb = (char*)&Xs[buf ^ 1][0][0];
#pragma unroll
            for (int t = 0; t < 26; ++t)
                GLOAD_LDS4(cb + voff[t], lb + (wv + 4 * t) * 256);
            asm volatile("s_waitcnt vmcnt(26)" ::: "memory");  // cur chunk landed
        } else {
            asm volatile("s_waitcnt vmcnt(0)" ::: "memory");
        }
        __builtin_amdgcn_sched_barrier(0);
        __builtin_amdgcn_s_barrier();              // all waves' cur loads visible
        __builtin_amdgcn_sched_barrier(0);

#pragma unroll 1
        for (int ci = 0; ci < 8; ++ci) {
            const int cin = cc * 8 + ci;
#pragma unroll
            for (int kh = 0; kh < 5; ++kh) {
                const int r0 = 2 * wv + kh;
                float x0[5], x1[5];
#pragma unroll
                for (int kw = 0; kw < 5; ++kw) {
                    x0[kw] = Xs[buf][ci][r0 * 68 + lane + kw];
                    x1[kw] = Xs[buf][ci][(r0 + 1) * 68 + lane + kw];
                }
                const float* wr = wpk + (size_t)((cin * 5 + kh) * 5) * COUT + cob;
#pragma unroll
                for (int kw = 0; kw < 5; ++kw)
#pragma unroll
                    for (int c = 0; c < 32; ++c) {
                        const float wt = wr[kw * COUT + c];   // block-uniform -> s_load
                        acc[0][c] = fmaf(x0[kw], wt, acc[0][c]);
                        acc[1][c] = fmaf(x1[kw], wt, acc[1][c]);
                    }
            }
        }
        asm volatile("s_waitcnt lgkmcnt(0)" ::: "memory");
        __builtin_amdgcn_s_barrier();              // reads done before next overwrite
        __builtin_amdgcn_sched_barrier(0);
    }

    float* yb = y1 + ((size_t)b * COUT + cob) * PLANE;
#pragma unroll
    for (int rr = 0; rr < 2; ++rr) {
        const int hh = h0 + 2 * wv + rr;
#pragma unroll
        for (int c = 0; c < 32; ++c)
            yb[(size_t)c * PLANE + hh * WW + (w0 + lane)] = acc[rr][c];
    }
}

// K2: fused depthwise 5x5 DoG (zero pad) + winner-take-all, two-pass recompute.
// Block: 16 rows x 64 cols, 256 threads (thread = 4 rows x 1 col).
// Per channel: reg-staged (issue-early) double-buffered LDS tile [20][68].
// pass1: track per-pixel running max over 64 channels; pass2: recompute DoG
// (bitwise-identical) and write (v >= max) ? v : 0.
// grid: (16 tiles [8 h-bands x 2 w-bands], 32 batch)
__global__ __launch_bounds__(256) void dog_wta(const float* __restrict__ y1,
                                               float* __restrict__ out) {
    __shared__ float T[2][1536];                   // 2 x 6144 B (1360 used + pad)
    __shared__ float dks[25];
    const int tid = threadIdx.x;
    if (tid < 25) {
        const int i = tid / 5, j = tid % 5;
        const double dx = i - 2, dy = j - 2;
        const double r2 = dx * dx + dy * dy;
        const double se2 = 2.0 * 1.2 * 1.2, si2 = 2.0 * 1.4 * 1.4;
        const double pi = 3.14159265358979323846;
        const double ge = exp(-r2 / se2) / (pi * se2);
        const double gi = exp(-r2 / si2) / (pi * si2);
        const double c0 = 1.0 / (pi * se2) - 1.0 / (pi * si2);
        dks[tid] = (float)((ge - gi) / c0);
    }
    __syncthreads();
    float dkr[25];
#pragma unroll
    for (int k = 0; k < 25; ++k) dkr[k] = dks[k];  // kernel taps in registers

    const int col = tid & 63;
    const int lr  = (tid >> 6) * 4;                // thread's 4 rows: lr..lr+3
    const int h0  = (int)(blockIdx.x >> 1) * 16;
    const int w0  = (int)(blockIdx.x & 1) * 64;
    const int b   = (int)blockIdx.y;
    const float* yb = y1 + (size_t)b * COUT * PLANE;
    float* ob = out + (size_t)b * COUT * PLANE;

    // stage geometry: element e = tid + k*256 -> (r,c) in [20][68] halo tile;
    // zero-pad handled via goff = -1 sentinel (value cndmask at load).
    int goff[6];
#pragma unroll
    for (int k = 0; k < 6; ++k) {
        const int e = tid + k * 256;
        const int r = e / 68, c = e - (e / 68) * 68;
        const int gr = h0 - 2 + r, gc = w0 - 2 + c;
        goff[k] = (e < 1360 && (unsigned)gr < HH && (unsigned)gc < WW)
                    ? (gr * WW + gc) : -1;
    }

    float mx[4];
#pragma unroll
    for (int r = 0; r < 4; ++r) mx[r] = -INFINITY;

    float rs[6];
#pragma unroll 1
    for (int pass = 0; pass < 2; ++pass) {
#pragma unroll
        for (int k = 0; k < 6; ++k) rs[k] = (goff[k] >= 0) ? yb[goff[k]] : 0.f;
#pragma unroll 1
        for (int ch = 0; ch < 64; ++ch) {
            float* Tb = T[ch & 1];
#pragma unroll
            for (int k = 0; k < 6; ++k) Tb[tid + k * 256] = rs[k];
            if (ch < 63) {                         // issue next channel's loads early
                const float* yc = yb + (size_t)(ch + 1) * PLANE;
#pragma unroll
                for (int k = 0; k < 6; ++k) rs[k] = (goff[k] >= 0) ? yc[goff[k]] : 0.f;
            }
            asm volatile("s_waitcnt lgkmcnt(0)" ::: "memory"); // ds_writes visible
            __builtin_amdgcn_s_barrier();          // no vmcnt drain: loads in flight
            __builtin_amdgcn_sched_barrier(0);

            float xr[8][5];
#pragma unroll
            for (int q = 0; q < 8; ++q)
#pragma unroll
                for (int kw = 0; kw < 5; ++kw)
                    xr[q][kw] = Tb[(lr + q) * 68 + col + kw];
#pragma unroll
            for (int rr = 0; rr < 4; ++rr) {
                float s = 0.f;
#pragma unroll
                for (int kh = 0; kh < 5; ++kh)
#pragma unroll
                    for (int kw = 0; kw < 5; ++kw)
                        s = fmaf(xr[rr + kh][kw], dkr[kh * 5 + kw], s);
                if (pass == 0) {
                    mx[rr] = fmaxf(mx[rr], s);
                } else {
                    const float o = (s >= mx[rr]) ? s : 0.f;
                    ob[(size_t)ch * PLANE + (size_t)(h0 + lr + rr) * WW + w0 + col] = o;
                }
            }
        }
    }
}

extern "C" void kernel_launch(void* const* d_in, const int* in_sizes, int n_in,
                              void* d_out, int out_size, void* d_ws, size_t ws_size,
                              hipStream_t stream) {
    const float* x = (const float*)d_in[0];        // [32,32,128,128]
    const float* w = (const float*)d_in[1];        // [64,32,5,5]
    float* out = (float*)d_out;                    // [32,64,128,128]

    float* y1  = (float*)d_ws;                     // 134217728 B
    float* wpk = (float*)((char*)d_ws + (size_t)BB * COUT * PLANE * 4);

    repack_w<<<(COUT * CIN * 25 + 255) / 256, 256, 0, stream>>>(w, wpk);
    conv_main<<<dim3(32, 2, BB), 256, 0, stream>>>(x, wpk, y1);
    dog_wta<<<dim3(16, BB), 256, 0, stream>>>(y1, out);
}

// Round 7
// 2483.528 us; speedup vs baseline: 1.1461x; 1.1461x over previous
//
#include <hip/hip_runtime.h>
#include <math.h>

#define BB   32
#define CIN  32
#define COUT 64
#define HH   128
#define WW   128
#define PLANE (HH*WW)          // 16384

// symmetric padding index map (size 128, pad 2)
__device__ __forceinline__ int reflect(int p) {
    if (p < 0)   return -1 - p;      // -1->0, -2->1
    if (p > 127) return 255 - p;     // 128->127, 129->126
    return p;
}

// K0: repack weight [co][cin][kh][kw] -> wpk [(cin*25+k)][co]  (co fastest)
__global__ __launch_bounds__(256) void repack_w(const float* __restrict__ w,
                                                float* __restrict__ wpk) {
    int i = blockIdx.x * 256 + threadIdx.x;        // over 64*32*25 = 51200
    if (i >= COUT * CIN * 25) return;
    int co = i / (CIN * 25);
    int rm = i - co * (CIN * 25);                  // cin*25 + k
    wpk[rm * COUT + co] = w[i];
}

// K1: main 5x5 conv, symmetric pad.
// Block: 8 rows x 64 cols x 32 couts; 4 waves, wave wv owns rows 2wv,2wv+1.
// Staging: reg-staged prefetch (13 regs/thread, flat goff[13] map), LDS
// double-buffered [2][3328] floats, ONE raw s_barrier per 4-cin chunk
// (dog_wta-proven pattern: lgkmcnt(0)+s_barrier, global loads stay in flight;
// NO __syncthreads in the loop -> no vmcnt(0) drain).
// grid: (32 tiles [16 h-tiles x 2 w-tiles], 2 cout-blocks, 32 batch)
__global__ __launch_bounds__(256, 4) void conv_main(const float* __restrict__ x,
                                                    const float* __restrict__ wpk,
                                                    float* __restrict__ y1) {
    __shared__ float Xs[2][3328];                  // 2 x 13312 B = 26624 B
    const int tid  = threadIdx.x;
    const int lane = tid & 63;
    const int wv   = tid >> 6;                     // wave 0..3
    const int h0   = (int)(blockIdx.x >> 1) * 8;
    const int w0   = (int)(blockIdx.x & 1) * 64;
    const int cob  = (int)blockIdx.y * 32;
    const int b    = (int)blockIdx.z;

    const float* xb = x + (size_t)b * CIN * PLANE;

    // flat staging map: element e = tid + 256k over [4 ci][12 r][68 c] (3264);
    // reflect folded in; tail e>=3264 -> harmless offset 0 (junk LDS never read)
    int goff[13];
#pragma unroll
    for (int k = 0; k < 13; ++k) {
        const int e  = tid + 256 * k;
        const int ci = e / 816;                    // 816 = 12*68
        const int ep = e - ci * 816;
        const int r  = ep / 68;
        const int c  = ep - r * 68;
        goff[k] = (e < 3264)
                    ? (ci * PLANE + reflect(h0 - 2 + r) * WW + reflect(w0 - 2 + c))
                    : 0;
    }

    float acc[2][32];
#pragma unroll
    for (int r = 0; r < 2; ++r)
#pragma unroll
        for (int c = 0; c < 32; ++c) acc[r][c] = 0.f;

    // prologue: load chunk 0 into regs
    float rs[13];
#pragma unroll
    for (int k = 0; k < 13; ++k) rs[k] = xb[goff[k]];

#pragma unroll 1
    for (int cc = 0; cc < 8; ++cc) {               // 8 chunks of 4 cin
        float* Tb = Xs[cc & 1];
#pragma unroll
        for (int k = 0; k < 13; ++k)               // waits rs (landed long ago)
            Tb[tid + 256 * k] = rs[k];
        if (cc < 7) {                              // issue next chunk's loads early
            const float* xn = xb + (size_t)(cc + 1) * 4 * PLANE;
#pragma unroll
            for (int k = 0; k < 13; ++k) rs[k] = xn[goff[k]];
        }
        asm volatile("s_waitcnt lgkmcnt(0)" ::: "memory");  // ds_writes visible
        __builtin_amdgcn_s_barrier();              // raw: vmcnt loads stay in flight
        __builtin_amdgcn_sched_barrier(0);

#pragma unroll 1
        for (int ci = 0; ci < 4; ++ci) {
            const int cin = cc * 4 + ci;
            const float* Tc = Tb + ci * 816;
#pragma unroll
            for (int kh = 0; kh < 5; ++kh) {
                const int r0 = 2 * wv + kh;
                float x0[5], x1[5];
#pragma unroll
                for (int kw = 0; kw < 5; ++kw) {
                    x0[kw] = Tc[r0 * 68 + lane + kw];
                    x1[kw] = Tc[(r0 + 1) * 68 + lane + kw];
                }
                const float* wr = wpk + (size_t)((cin * 5 + kh) * 5) * COUT + cob;
#pragma unroll
                for (int kw = 0; kw < 5; ++kw)
#pragma unroll
                    for (int c = 0; c < 32; ++c) {
                        const float wt = wr[kw * COUT + c];   // block-uniform -> s_load
                        acc[0][c] = fmaf(x0[kw], wt, acc[0][c]);
                        acc[1][c] = fmaf(x1[kw], wt, acc[1][c]);
                    }
            }
        }
        // WAR on Xs[cc&1] is protected by next iteration's lgkmcnt(0)+barrier
    }

    float* yb = y1 + ((size_t)b * COUT + cob) * PLANE;
#pragma unroll
    for (int rr = 0; rr < 2; ++rr) {
        const int hh = h0 + 2 * wv + rr;
#pragma unroll
        for (int c = 0; c < 32; ++c)
            yb[(size_t)c * PLANE + hh * WW + (w0 + lane)] = acc[rr][c];
    }
}

// K2: fused depthwise 5x5 DoG (zero pad) + winner-take-all, two-pass recompute.
// Block: 16 rows x 64 cols, 256 threads (thread = 4 rows x 1 col).
// Per channel: reg-staged (issue-early) double-buffered LDS tile [20][68].
// pass1: track per-pixel running max over 64 channels; pass2: recompute DoG
// (bitwise-identical) and write (v >= max) ? v : 0.
// grid: (16 tiles [8 h-bands x 2 w-bands], 32 batch)   [R5-verified: ~147 us]
__global__ __launch_bounds__(256) void dog_wta(const float* __restrict__ y1,
                                               float* __restrict__ out) {
    __shared__ float T[2][1536];                   // 2 x 6144 B (1360 used + pad)
    __shared__ float dks[25];
    const int tid = threadIdx.x;
    if (tid < 25) {
        const int i = tid / 5, j = tid % 5;
        const double dx = i - 2, dy = j - 2;
        const double r2 = dx * dx + dy * dy;
        const double se2 = 2.0 * 1.2 * 1.2, si2 = 2.0 * 1.4 * 1.4;
        const double pi = 3.14159265358979323846;
        const double ge = exp(-r2 / se2) / (pi * se2);
        const double gi = exp(-r2 / si2) / (pi * si2);
        const double c0 = 1.0 / (pi * se2) - 1.0 / (pi * si2);
        dks[tid] = (float)((ge - gi) / c0);
    }
    __syncthreads();
    float dkr[25];
#pragma unroll
    for (int k = 0; k < 25; ++k) dkr[k] = dks[k];  // kernel taps in registers

    const int col = tid & 63;
    const int lr  = (tid >> 6) * 4;                // thread's 4 rows: lr..lr+3
    const int h0  = (int)(blockIdx.x >> 1) * 16;
    const int w0  = (int)(blockIdx.x & 1) * 64;
    const int b   = (int)blockIdx.y;
    const float* yb = y1 + (size_t)b * COUT * PLANE;
    float* ob = out + (size_t)b * COUT * PLANE;

    // stage geometry: element e = tid + k*256 -> (r,c) in [20][68] halo tile;
    // zero-pad handled via goff = -1 sentinel (value cndmask at load).
    int goff[6];
#pragma unroll
    for (int k = 0; k < 6; ++k) {
        const int e = tid + k * 256;
        const int r = e / 68, c = e - (e / 68) * 68;
        const int gr = h0 - 2 + r, gc = w0 - 2 + c;
        goff[k] = (e < 1360 && (unsigned)gr < HH && (unsigned)gc < WW)
                    ? (gr * WW + gc) : -1;
    }

    float mx[4];
#pragma unroll
    for (int r = 0; r < 4; ++r) mx[r] = -INFINITY;

    float rs[6];
#pragma unroll 1
    for (int pass = 0; pass < 2; ++pass) {
#pragma unroll
        for (int k = 0; k < 6; ++k) rs[k] = (goff[k] >= 0) ? yb[goff[k]] : 0.f;
#pragma unroll 1
        for (int ch = 0; ch < 64; ++ch) {
            float* Tb = T[ch & 1];
#pragma unroll
            for (int k = 0; k < 6; ++k) Tb[tid + k * 256] = rs[k];
            if (ch < 63) {                         // issue next channel's loads early
                const float* yc = yb + (size_t)(ch + 1) * PLANE;
#pragma unroll
                for (int k = 0; k < 6; ++k) rs[k] = (goff[k] >= 0) ? yc[goff[k]] : 0.f;
            }
            asm volatile("s_waitcnt lgkmcnt(0)" ::: "memory"); // ds_writes visible
            __builtin_amdgcn_s_barrier();          // no vmcnt drain: loads in flight
            __builtin_amdgcn_sched_barrier(0);

            float xr[8][5];
#pragma unroll
            for (int q = 0; q < 8; ++q)
#pragma unroll
                for (int kw = 0; kw < 5; ++kw)
                    xr[q][kw] = Tb[(lr + q) * 68 + col + kw];
#pragma unroll
            for (int rr = 0; rr < 4; ++rr) {
                float s = 0.f;
#pragma unroll
                for (int kh = 0; kh < 5; ++kh)
#pragma unroll
                    for (int kw = 0; kw < 5; ++kw)
                        s = fmaf(xr[rr + kh][kw], dkr[kh * 5 + kw], s);
                if (pass == 0) {
                    mx[rr] = fmaxf(mx[rr], s);
                } else {
                    const float o = (s >= mx[rr]) ? s : 0.f;
                    ob[(size_t)ch * PLANE + (size_t)(h0 + lr + rr) * WW + w0 + col] = o;
                }
            }
        }
    }
}

extern "C" void kernel_launch(void* const* d_in, const int* in_sizes, int n_in,
                              void* d_out, int out_size, void* d_ws, size_t ws_size,
                              hipStream_t stream) {
    const float* x = (const float*)d_in[0];        // [32,32,128,128]
    const float* w = (const float*)d_in[1];        // [64,32,5,5]
    float* out = (float*)d_out;                    // [32,64,128,128]

    float* y1  = (float*)d_ws;                     // 134217728 B
    float* wpk = (float*)((char*)d_ws + (size_t)BB * COUT * PLANE * 4);

    repack_w<<<(COUT * CIN * 25 + 255) / 256, 256, 0, stream>>>(w, wpk);
    conv_main<<<dim3(32, 2, BB), 256, 0, stream>>>(x, wpk, y1);
    dog_wta<<<dim3(16, BB), 256, 0, stream>>>(y1, out);
}

// Round 8
// 2332.314 us; speedup vs baseline: 1.2204x; 1.0648x over previous
//
#include <hip/hip_runtime.h>
#include <math.h>

#define BB   32
#define CIN  32
#define COUT 64
#define HH   128
#define WW   128
#define PLANE (HH*WW)          // 16384

// symmetric padding index map (size 128, pad 2)
__device__ __forceinline__ int reflect(int p) {
    if (p < 0)   return -1 - p;      // -1->0, -2->1
    if (p > 127) return 255 - p;     // 128->127, 129->126
    return p;
}

// K0: repack weight [co][cin][kh][kw] -> wpk [(cin*25+k)][co]  (co fastest)
__global__ __launch_bounds__(256) void repack_w(const float* __restrict__ w,
                                                float* __restrict__ wpk) {
    int i = blockIdx.x * 256 + threadIdx.x;        // over 64*32*25 = 51200
    if (i >= COUT * CIN * 25) return;
    int co = i / (CIN * 25);
    int rm = i - co * (CIN * 25);                  // cin*25 + k
    wpk[rm * COUT + co] = w[i];
}

// K1: main 5x5 conv, symmetric pad — PLAIN-HIP double-buffered pipeline.
// Block: 8 rows x 64 cols x 32 couts; 4 waves, wave wv owns rows 2wv,2wv+1.
// Per 2-cin chunk: issue 7 global loads (next chunk) -> compute 3200 FMAs
// from LDS buf A -> ds_write staged regs to buf B -> __syncthreads.
// Loads have the whole compute phase to land, so waits are ~free.
// No inline asm / no sched_barrier / no launch_bounds cap (R5/R7 lesson:
// those caused spill storms; WRITE_SIZE is the spill canary).
// grid: (32 tiles [16 h-tiles x 2 w-tiles], 2 cout-blocks, 32 batch)
__global__ __launch_bounds__(256) void conv_main(const float* __restrict__ x,
                                                 const float* __restrict__ wpk,
                                                 float* __restrict__ y1) {
    __shared__ float Xs[2][1792];                  // 2 x 7168 B = 14336 B
    const int tid  = threadIdx.x;
    const int lane = tid & 63;
    const int wv   = tid >> 6;                     // wave 0..3
    const int h0   = (int)(blockIdx.x >> 1) * 8;
    const int w0   = (int)(blockIdx.x & 1) * 64;
    const int cob  = (int)blockIdx.y * 32;
    const int b    = (int)blockIdx.z;

    const float* xb = x + (size_t)b * CIN * PLANE;

    // flat staging map: element e = tid + 256k over [2 ci][12 r][68 c] (1632);
    // reflect folded in; tail e>=1632 -> harmless offset 0 (junk LDS never read)
    int goff[7];
#pragma unroll
    for (int k = 0; k < 7; ++k) {
        const int e  = tid + 256 * k;
        const int ci = e / 816;                    // 816 = 12*68
        const int ep = e - ci * 816;
        const int r  = ep / 68;
        const int c  = ep - r * 68;
        goff[k] = (e < 1632)
                    ? (ci * PLANE + reflect(h0 - 2 + r) * WW + reflect(w0 - 2 + c))
                    : 0;
    }

    float acc[2][32];
#pragma unroll
    for (int r = 0; r < 2; ++r)
#pragma unroll
        for (int c = 0; c < 32; ++c) acc[r][c] = 0.f;

    // prologue: chunk 0 -> regs -> LDS buf 0
    {
        float rs[7];
#pragma unroll
        for (int k = 0; k < 7; ++k) rs[k] = xb[goff[k]];
#pragma unroll
        for (int k = 0; k < 7; ++k) Xs[0][tid + 256 * k] = rs[k];
    }
    __syncthreads();

#pragma unroll 1
    for (int cc = 0; cc < 16; ++cc) {              // 16 chunks of 2 cin
        float nrs[7];
        if (cc < 15) {                             // issue next chunk's loads early
            const float* xn = xb + (size_t)(cc + 1) * 2 * PLANE;
#pragma unroll
            for (int k = 0; k < 7; ++k) nrs[k] = xn[goff[k]];
        }
        const float* Tb = Xs[cc & 1];
#pragma unroll
        for (int ci = 0; ci < 2; ++ci) {
            const int cin = cc * 2 + ci;
            const float* Tc = Tb + ci * 816;
#pragma unroll
            for (int kh = 0; kh < 5; ++kh) {
                const int r0 = 2 * wv + kh;
                float x0[5], x1[5];
#pragma unroll
                for (int kw = 0; kw < 5; ++kw) {
                    x0[kw] = Tc[r0 * 68 + lane + kw];
                    x1[kw] = Tc[(r0 + 1) * 68 + lane + kw];
                }
                const float* wr = wpk + (size_t)((cin * 5 + kh) * 5) * COUT + cob;
#pragma unroll
                for (int kw = 0; kw < 5; ++kw)
#pragma unroll
                    for (int c = 0; c < 32; ++c) {
                        const float wt = wr[kw * COUT + c];   // block-uniform -> s_load
                        acc[0][c] = fmaf(x0[kw], wt, acc[0][c]);
                        acc[1][c] = fmaf(x1[kw], wt, acc[1][c]);
                    }
            }
        }
        if (cc < 15) {                             // write-late: loads landed by now
            float* Tn = Xs[(cc + 1) & 1];
#pragma unroll
            for (int k = 0; k < 7; ++k) Tn[tid + 256 * k] = nrs[k];
        }
        __syncthreads();                           // orders reads(bufA)/writes(bufB)
    }

    float* yb = y1 + ((size_t)b * COUT + cob) * PLANE;
#pragma unroll
    for (int rr = 0; rr < 2; ++rr) {
        const int hh = h0 + 2 * wv + rr;
#pragma unroll
        for (int c = 0; c < 32; ++c)
            yb[(size_t)c * PLANE + hh * WW + (w0 + lane)] = acc[rr][c];
    }
}

// K2: fused depthwise 5x5 DoG (zero pad) + winner-take-all, two-pass recompute.
// Block: 16 rows x 64 cols, 256 threads (thread = 4 rows x 1 col).
// Per channel: reg-staged (issue-early) double-buffered LDS tile [20][68].
// pass1: track per-pixel running max over 64 channels; pass2: recompute DoG
// (bitwise-identical) and write (v >= max) ? v : 0.
// grid: (16 tiles [8 h-bands x 2 w-bands], 32 batch)  [R5/R7-verified ~147 us]
__global__ __launch_bounds__(256) void dog_wta(const float* __restrict__ y1,
                                               float* __restrict__ out) {
    __shared__ float T[2][1536];                   // 2 x 6144 B (1360 used + pad)
    __shared__ float dks[25];
    const int tid = threadIdx.x;
    if (tid < 25) {
        const int i = tid / 5, j = tid % 5;
        const double dx = i - 2, dy = j - 2;
        const double r2 = dx * dx + dy * dy;
        const double se2 = 2.0 * 1.2 * 1.2, si2 = 2.0 * 1.4 * 1.4;
        const double pi = 3.14159265358979323846;
        const double ge = exp(-r2 / se2) / (pi * se2);
        const double gi = exp(-r2 / si2) / (pi * si2);
        const double c0 = 1.0 / (pi * se2) - 1.0 / (pi * si2);
        dks[tid] = (float)((ge - gi) / c0);
    }
    __syncthreads();
    float dkr[25];
#pragma unroll
    for (int k = 0; k < 25; ++k) dkr[k] = dks[k];  // kernel taps in registers

    const int col = tid & 63;
    const int lr  = (tid >> 6) * 4;                // thread's 4 rows: lr..lr+3
    const int h0  = (int)(blockIdx.x >> 1) * 16;
    const int w0  = (int)(blockIdx.x & 1) * 64;
    const int b   = (int)blockIdx.y;
    const float* yb = y1 + (size_t)b * COUT * PLANE;
    float* ob = out + (size_t)b * COUT * PLANE;

    // stage geometry: element e = tid + k*256 -> (r,c) in [20][68] halo tile;
    // zero-pad handled via goff = -1 sentinel (value cndmask at load).
    int goff[6];
#pragma unroll
    for (int k = 0; k < 6; ++k) {
        const int e = tid + k * 256;
        const int r = e / 68, c = e - (e / 68) * 68;
        const int gr = h0 - 2 + r, gc = w0 - 2 + c;
        goff[k] = (e < 1360 && (unsigned)gr < HH && (unsigned)gc < WW)
                    ? (gr * WW + gc) : -1;
    }

    float mx[4];
#pragma unroll
    for (int r = 0; r < 4; ++r) mx[r] = -INFINITY;

    float rs[6];
#pragma unroll 1
    for (int pass = 0; pass < 2; ++pass) {
#pragma unroll
        for (int k = 0; k < 6; ++k) rs[k] = (goff[k] >= 0) ? yb[goff[k]] : 0.f;
#pragma unroll 1
        for (int ch = 0; ch < 64; ++ch) {
            float* Tb = T[ch & 1];
#pragma unroll
            for (int k = 0; k < 6; ++k) Tb[tid + k * 256] = rs[k];
            if (ch < 63) {                         // issue next channel's loads early
                const float* yc = yb + (size_t)(ch + 1) * PLANE;
#pragma unroll
                for (int k = 0; k < 6; ++k) rs[k] = (goff[k] >= 0) ? yc[goff[k]] : 0.f;
            }
            asm volatile("s_waitcnt lgkmcnt(0)" ::: "memory"); // ds_writes visible
            __builtin_amdgcn_s_barrier();          // no vmcnt drain: loads in flight
            __builtin_amdgcn_sched_barrier(0);

            float xr[8][5];
#pragma unroll
            for (int q = 0; q < 8; ++q)
#pragma unroll
                for (int kw = 0; kw < 5; ++kw)
                    xr[q][kw] = Tb[(lr + q) * 68 + col + kw];
#pragma unroll
            for (int rr = 0; rr < 4; ++rr) {
                float s = 0.f;
#pragma unroll
                for (int kh = 0; kh < 5; ++kh)
#pragma unroll
                    for (int kw = 0; kw < 5; ++kw)
                        s = fmaf(xr[rr + kh][kw], dkr[kh * 5 + kw], s);
                if (pass == 0) {
                    mx[rr] = fmaxf(mx[rr], s);
                } else {
                    const float o = (s >= mx[rr]) ? s : 0.f;
                    ob[(size_t)ch * PLANE + (size_t)(h0 + lr + rr) * WW + w0 + col] = o;
                }
            }
        }
    }
}

extern "C" void kernel_launch(void* const* d_in, const int* in_sizes, int n_in,
                              void* d_out, int out_size, void* d_ws, size_t ws_size,
                              hipStream_t stream) {
    const float* x = (const float*)d_in[0];        // [32,32,128,128]
    const float* w = (const float*)d_in[1];        // [64,32,5,5]
    float* out = (float*)d_out;                    // [32,64,128,128]

    float* y1  = (float*)d_ws;                     // 134217728 B
    float* wpk = (float*)((char*)d_ws + (size_t)BB * COUT * PLANE * 4);

    repack_w<<<(COUT * CIN * 25 + 255) / 256, 256, 0, stream>>>(w, wpk);
    conv_main<<<dim3(32, 2, BB), 256, 0, stream>>>(x, wpk, y1);
    dog_wta<<<dim3(16, BB), 256, 0, stream>>>(y1, out);
}